// Round 2
// baseline (2690.935 us; speedup 1.0000x reference)
//
#include <hip/hip_runtime.h>
#include <hip/hip_bf16.h>

using bf16 = __hip_bfloat16;

#define BATCH 128
#define CCH   256
#define HWSZ  784      // 28*28
#define HID   512
#define NHD   8
#define KDIM  16
#define DDIM  32
#define NTOK  49
#define NWIN  2048     // 128 * 4 * 4
#define YPOS  (NWIN * NTOK)  // 100352

__device__ __forceinline__ float toF(float v) { return v; }
__device__ __forceinline__ float toF(bf16 v) { return __bfloat162float(v); }
__device__ __forceinline__ void storeF(float* p, float v) { *p = v; }
__device__ __forceinline__ void storeF(bf16* p, float v) { *p = __float2bfloat16(v); }

// ---------------------------------------------------------------------------
// Depthwise 3x3 + affine + residual:  out = x + s[c]*conv3x3(x) + b[c]
// One block per (b,c) plane; 30x30 zero-padded LDS tile.
// ---------------------------------------------------------------------------
__global__ __launch_bounds__(256) void dw3_k(const float* __restrict__ X,
                                             const float* __restrict__ Wg,
                                             const float* __restrict__ sc,
                                             const float* __restrict__ bi,
                                             float* __restrict__ out) {
    __shared__ float sp[30 * 30];
    const int plane = blockIdx.x;        // b*256 + c
    const int c = plane & 255;
    const size_t base = (size_t)plane * HWSZ;
    const int t = threadIdx.x;

    for (int i = t; i < 900; i += 256) sp[i] = 0.f;
    __syncthreads();
    for (int i = t; i < 784; i += 256) {
        int h = i / 28, w = i - h * 28;
        sp[(h + 1) * 30 + (w + 1)] = X[base + i];
    }
    __syncthreads();

    float wv[9];
#pragma unroll
    for (int k = 0; k < 9; ++k) wv[k] = Wg[c * 9 + k];
    const float s = sc[c];
    const float bb = bi[c];

    for (int i = t; i < 784; i += 256) {
        int h = i / 28, w = i - h * 28;
        float acc = 0.f;
#pragma unroll
        for (int u = 0; u < 3; ++u)
#pragma unroll
            for (int v = 0; v < 3; ++v)
                acc += wv[u * 3 + v] * sp[(h + u) * 30 + (w + v)];
        out[base + i] = sp[(h + 1) * 30 + (w + 1)] + s * acc + bb;
    }
}

// ---------------------------------------------------------------------------
// Generic conv1x1 GEMM: Out[oc,g] = s[oc]*(sum_ic W[oc,ic]*X[ic,g]) + b[oc]
// 64x64 tile, 256 threads, 4x4 microtile, K-chunk=16 via LDS.
// REMAP: columns g are windowed (w*49+p) -> scatter to NCHW for out/res.
// ---------------------------------------------------------------------------
template <typename TX, typename TOut, bool RELU_IN, bool RELU_OUT, bool RESID, bool REMAP>
__global__ __launch_bounds__(256) void conv1x1_k(const TX* __restrict__ X,
                                                 const float* __restrict__ Wg,
                                                 const float* __restrict__ sc,
                                                 const float* __restrict__ bi,
                                                 const float* __restrict__ res,
                                                 TOut* __restrict__ out,
                                                 int IC, int POSB) {
    __shared__ float Xs[16][68];
    __shared__ float Ws[16][68];
    const int t = threadIdx.x;
    const int tx = t & 15, ty = t >> 4;
    const int p0 = blockIdx.x * 64;
    const int oc0 = blockIdx.y * 64;
    const int b = blockIdx.z;
    const int OC = gridDim.y * 64;

    float acc[4][4] = {};
    const int lp = t & 63, lk = t >> 6;   // X staging: p=lp, k=lk+4r
    const int wk = t & 15, wo = t >> 4;   // W staging: k=wk, oc=wo+16r

    for (int ic0 = 0; ic0 < IC; ic0 += 16) {
#pragma unroll
        for (int r = 0; r < 4; ++r) {
            int kk = lk + r * 4;
            int gp = p0 + lp;
            float v = 0.f;
            if (gp < POSB) {
                v = toF(X[((size_t)(b * IC + ic0 + kk)) * POSB + gp]);
                if constexpr (RELU_IN) v = fmaxf(v, 0.f);
            }
            Xs[kk][lp] = v;
        }
#pragma unroll
        for (int r = 0; r < 4; ++r) {
            int occ = wo + r * 16;
            Ws[wk][occ] = Wg[(size_t)(oc0 + occ) * IC + ic0 + wk];
        }
        __syncthreads();
#pragma unroll
        for (int kk = 0; kk < 16; ++kk) {
            float4 xv = *(const float4*)&Xs[kk][tx * 4];
            float4 wv = *(const float4*)&Ws[kk][ty * 4];
            acc[0][0] += wv.x * xv.x; acc[0][1] += wv.x * xv.y;
            acc[0][2] += wv.x * xv.z; acc[0][3] += wv.x * xv.w;
            acc[1][0] += wv.y * xv.x; acc[1][1] += wv.y * xv.y;
            acc[1][2] += wv.y * xv.z; acc[1][3] += wv.y * xv.w;
            acc[2][0] += wv.z * xv.x; acc[2][1] += wv.z * xv.y;
            acc[2][2] += wv.z * xv.z; acc[2][3] += wv.z * xv.w;
            acc[3][0] += wv.w * xv.x; acc[3][1] += wv.w * xv.y;
            acc[3][2] += wv.w * xv.z; acc[3][3] += wv.w * xv.w;
        }
        __syncthreads();
    }

#pragma unroll
    for (int j = 0; j < 4; ++j) {
        int oc = oc0 + ty * 4 + j;
        float s = sc[oc];
        float bb = bi[oc];
#pragma unroll
        for (int i = 0; i < 4; ++i) {
            int g = p0 + tx * 4 + i;
            if (g >= POSB) continue;
            float v = s * acc[j][i] + bb;
            if constexpr (RELU_OUT) v = fmaxf(v, 0.f);
            size_t oidx;
            if constexpr (REMAP) {
                int w = g / 49, p = g - w * 49;
                int wb = w >> 4, wh = (w >> 2) & 3, wwi = w & 3;
                int pi = p / 7, pj = p - pi * 7;
                oidx = ((size_t)(wb * OC + oc)) * HWSZ + (wh * 7 + pi) * 28 + wwi * 7 + pj;
            } else {
                oidx = ((size_t)(b * OC + oc)) * POSB + g;
            }
            if constexpr (RESID) v += res[oidx];
            storeF(&out[oidx], v);
        }
    }
}

// ---------------------------------------------------------------------------
// Cascaded group attention: one block per 7x7 window, full 8-head cascade in
// LDS. Writes y in channel-major windowed layout Y[ch][w*49+p] (bf16, pre-relu).
// ---------------------------------------------------------------------------
__global__ __launch_bounds__(256) void attn_k(const float* __restrict__ X,
                                              const float* __restrict__ qkvW,
                                              const float* __restrict__ qkvS,
                                              const float* __restrict__ qkvB,
                                              const float* __restrict__ dwW,
                                              const float* __restrict__ dwS,
                                              const float* __restrict__ dwB,
                                              const float* __restrict__ ab,
                                              const int* __restrict__ bidx,
                                              bf16* __restrict__ Y) {
    __shared__ float feat[32][49];
    __shared__ float f[64][49];     // q=f[0:16], k=f[16:32], v=f[32:64]
    __shared__ float q2[16][49];
    __shared__ float attn[49][50];
    __shared__ float qw[64 * 32];
    __shared__ float qs[64], qb[64];
    __shared__ float dwv[16 * 25];
    __shared__ float dss[16], dbb[16];
    __shared__ float abr[49];
    __shared__ int idx_s[49 * 49];

    const int t = threadIdx.x;
    const int w = blockIdx.x;
    const int b = w >> 4, wh = (w >> 2) & 3, wwi = w & 3;

    for (int i = t; i < 2401; i += 256) idx_s[i] = bidx[i];
    for (int i = t; i < 32 * 49; i += 256) {
        int c = i / 49, p = i - c * 49;
        int pi = p / 7, pj = p - pi * 7;
        feat[c][p] = X[((size_t)(b * 256 + c)) * HWSZ + (wh * 7 + pi) * 28 + wwi * 7 + pj];
    }
    __syncthreads();

    for (int head = 0; head < 8; ++head) {
        if (head > 0) {
            for (int i = t; i < 32 * 49; i += 256) {
                int c = i / 49, p = i - c * 49;
                int pi = p / 7, pj = p - pi * 7;
                feat[c][p] += X[((size_t)(b * 256 + head * 32 + c)) * HWSZ +
                                (wh * 7 + pi) * 28 + wwi * 7 + pj];
            }
        }
        for (int i = t; i < 2048; i += 256) qw[i] = qkvW[head * 2048 + i];
        if (t < 64) {
            qs[t] = qkvS[head * 64 + t];
            qb[t] = qkvB[head * 64 + t];
        }
        for (int i = t; i < 400; i += 256) dwv[i] = dwW[head * 400 + i];
        if (t < 16) {
            dss[t] = dwS[head * 16 + t];
            dbb[t] = dwB[head * 16 + t];
        }
        if (t < 49) abr[t] = ab[head * 49 + t];
        __syncthreads();

        // qkv 1x1: f[o][p] = qs[o]*sum_ic qw[o][ic]*feat[ic][p] + qb[o]
        for (int i = t; i < 64 * 49; i += 256) {
            int o = i / 49, p = i - o * 49;
            float a = 0.f;
#pragma unroll
            for (int ic = 0; ic < 32; ++ic) a += qw[o * 32 + ic] * feat[ic][p];
            f[o][p] = qs[o] * a + qb[o];
        }
        __syncthreads();

        // depthwise 5x5 on q (pad 2, zero outside window)
        for (int i = t; i < 16 * 49; i += 256) {
            int d = i / 49, p = i - d * 49;
            int pi = p / 7, pj = p - pi * 7;
            float a = 0.f;
            for (int u = 0; u < 5; ++u) {
                int ii = pi + u - 2;
                if (ii < 0 || ii >= 7) continue;
                for (int v = 0; v < 5; ++v) {
                    int jj = pj + v - 2;
                    if (jj < 0 || jj >= 7) continue;
                    a += dwv[d * 25 + u * 5 + v] * f[d][ii * 7 + jj];
                }
            }
            q2[d][p] = dss[d] * a + dbb[d];
        }
        __syncthreads();

        // logits: attn[n][m] = 0.25*sum_d q2[d][n]*k[d][m] + bias
        for (int i = t; i < 2401; i += 256) {
            int n = i / 49, m = i - n * 49;
            float a = 0.f;
#pragma unroll
            for (int d = 0; d < 16; ++d) a += q2[d][n] * f[16 + d][m];
            attn[n][m] = a * 0.25f + abr[idx_s[i]];
        }
        __syncthreads();

        // softmax over m, one row per thread
        if (t < 49) {
            float mx = -1e30f;
            for (int m = 0; m < 49; ++m) mx = fmaxf(mx, attn[t][m]);
            float sum = 0.f;
            for (int m = 0; m < 49; ++m) {
                float e = __expf(attn[t][m] - mx);
                attn[t][m] = e;
                sum += e;
            }
            float inv = 1.f / sum;
            for (int m = 0; m < 49; ++m) attn[t][m] *= inv;
        }
        __syncthreads();

        // out: feat[d][n] = sum_m v[d][m]*attn[n][m]; also emit to Y
        for (int i = t; i < 32 * 49; i += 256) {
            int d = i / 49, n = i - d * 49;
            float a = 0.f;
#pragma unroll
            for (int m = 0; m < 49; ++m) a += f[32 + d][m] * attn[n][m];
            feat[d][n] = a;
            Y[((size_t)(head * 32 + d)) * YPOS + (size_t)w * 49 + n] = __float2bfloat16(a);
        }
        __syncthreads();
    }
}

// ---------------------------------------------------------------------------
extern "C" void kernel_launch(void* const* d_in, const int* in_sizes, int n_in,
                              void* d_out, int out_size, void* d_ws, size_t ws_size,
                              hipStream_t stream) {
    const float* x       = (const float*)d_in[0];
    const float* dw0_w   = (const float*)d_in[1];
    const float* dw0_s   = (const float*)d_in[2];
    const float* dw0_b   = (const float*)d_in[3];
    const float* ffn0_w1 = (const float*)d_in[4];
    const float* ffn0_s1 = (const float*)d_in[5];
    const float* ffn0_b1 = (const float*)d_in[6];
    const float* ffn0_w2 = (const float*)d_in[7];
    const float* ffn0_s2 = (const float*)d_in[8];
    const float* ffn0_b2 = (const float*)d_in[9];
    const float* qkv_w   = (const float*)d_in[10];
    const float* qkv_s   = (const float*)d_in[11];
    const float* qkv_b   = (const float*)d_in[12];
    const float* dwq_w   = (const float*)d_in[13];
    const float* dwq_s   = (const float*)d_in[14];
    const float* dwq_b   = (const float*)d_in[15];
    const float* attn_b  = (const float*)d_in[16];
    const float* proj_w  = (const float*)d_in[17];
    const float* proj_s  = (const float*)d_in[18];
    const float* proj_b  = (const float*)d_in[19];
    const float* dw1_w   = (const float*)d_in[20];
    const float* dw1_s   = (const float*)d_in[21];
    const float* dw1_b   = (const float*)d_in[22];
    const float* ffn1_w1 = (const float*)d_in[23];
    const float* ffn1_s1 = (const float*)d_in[24];
    const float* ffn1_b1 = (const float*)d_in[25];
    const float* ffn1_w2 = (const float*)d_in[26];
    const float* ffn1_s2 = (const float*)d_in[27];
    const float* ffn1_b2 = (const float*)d_in[28];
    const int*   bidx    = (const int*)d_in[29];
    float* out = (float*)d_out;

    char* ws = (char*)d_ws;
    const size_t NEL = (size_t)BATCH * CCH * HWSZ;  // 25,690,112
    float* A   = (float*)ws;               // x1 / x3     : NEL f32
    bf16*  Hid = (bf16*)(ws + NEL * 4);    // hidden      : 2*NEL bf16 elems
    float* Bb  = (float*)(ws + NEL * 8);   // x2 / x4     : NEL f32
    bf16*  Yb  = (bf16*)(ws + NEL * 12);   // y windowed  : NEL bf16
    // total ws used: NEL*14 = 359,661,568 bytes

    // 1) x1 = x + dw3x3(x)
    dw3_k<<<BATCH * CCH, 256, 0, stream>>>(x, dw0_w, dw0_s, dw0_b, A);
    // 2) hid = relu(affine(W1 @ x1))
    conv1x1_k<float, bf16, false, true, false, false>
        <<<dim3(13, HID / 64, BATCH), 256, 0, stream>>>(A, ffn0_w1, ffn0_s1, ffn0_b1,
                                                        nullptr, Hid, CCH, HWSZ);
    // 3) x2 = x1 + affine(W2 @ hid)
    conv1x1_k<bf16, float, false, false, true, false>
        <<<dim3(13, CCH / 64, BATCH), 256, 0, stream>>>(Hid, ffn0_w2, ffn0_s2, ffn0_b2,
                                                        A, Bb, HID, HWSZ);
    // 4) cascaded window attention -> Yb (channel-major windowed, pre-relu)
    attn_k<<<NWIN, 256, 0, stream>>>(Bb, qkv_w, qkv_s, qkv_b, dwq_w, dwq_s, dwq_b,
                                     attn_b, bidx, Yb);
    // 5) x3 = x2 + affine(PW @ relu(y))   (window remap epilogue)
    conv1x1_k<bf16, float, true, false, true, true>
        <<<dim3(YPOS / 64, CCH / 64, 1), 256, 0, stream>>>(Yb, proj_w, proj_s, proj_b,
                                                           Bb, A, CCH, YPOS);
    // 6) x4 = x3 + dw3x3(x3)
    dw3_k<<<BATCH * CCH, 256, 0, stream>>>(A, dw1_w, dw1_s, dw1_b, Bb);
    // 7) hid = relu(affine(W1 @ x4))
    conv1x1_k<float, bf16, false, true, false, false>
        <<<dim3(13, HID / 64, BATCH), 256, 0, stream>>>(Bb, ffn1_w1, ffn1_s1, ffn1_b1,
                                                        nullptr, Hid, CCH, HWSZ);
    // 8) out = x4 + affine(W2 @ hid)  -> d_out (fp32)
    conv1x1_k<bf16, float, false, false, true, false>
        <<<dim3(13, CCH / 64, BATCH), 256, 0, stream>>>(Hid, ffn1_w2, ffn1_s2, ffn1_b2,
                                                        Bb, out, HID, HWSZ);
}

// Round 3
// 1918.938 us; speedup vs baseline: 1.4023x; 1.4023x over previous
//
#include <hip/hip_runtime.h>
#include <hip/hip_bf16.h>

using bf16 = __hip_bfloat16;
using short8 = __attribute__((ext_vector_type(8))) short;
using f32x4  = __attribute__((ext_vector_type(4))) float;

#define BATCH 128
#define CCH   256
#define HWSZ  784
#define NPOS  100352          // 128*784, NHWC row count; 100352/128 = 784 exactly
#define NWIN  2048

__device__ __forceinline__ ushort f2u(float f) {
    bf16 h = __float2bfloat16(f);
    return *reinterpret_cast<ushort*>(&h);
}
__device__ __forceinline__ float u2f(ushort u) {
    bf16 h;
    *reinterpret_cast<ushort*>(&h) = u;
    return __bfloat162float(h);
}

// ---------------------------------------------------------------------------
// Weight fp32 -> bf16 pre-convert (5 matrices concatenated).
// ---------------------------------------------------------------------------
__global__ __launch_bounds__(256) void wcvt_k(const float* __restrict__ w1a,
                                              const float* __restrict__ w2a,
                                              const float* __restrict__ pw,
                                              const float* __restrict__ w1b,
                                              const float* __restrict__ w2b,
                                              ushort* __restrict__ out) {
    int i = blockIdx.x * 256 + threadIdx.x;
    if (i >= 589824) return;
    float v;
    if (i < 131072)      v = w1a[i];
    else if (i < 262144) v = w2a[i - 131072];
    else if (i < 327680) v = pw[i - 262144];
    else if (i < 458752) v = w1b[i - 327680];
    else                 v = w2b[i - 458752];
    out[i] = f2u(v);
}

// ---------------------------------------------------------------------------
// NCHW fp32 -> NHWC bf16 transpose. Block = (pos-chunk of 112, batch).
// ---------------------------------------------------------------------------
__global__ __launch_bounds__(256) void tin_k(const float* __restrict__ X,
                                             ushort* __restrict__ O) {
    __shared__ ushort tile[256][113];
    const int pc = blockIdx.x, b = blockIdx.y;
    const int t = threadIdx.x;
    const size_t xbase = (size_t)b * 256 * 784 + pc * 112;
    for (int r = 0; r < 112; ++r) {
        int idx = r * 256 + t;
        int c = idx / 112, p = idx - c * 112;
        tile[c][p] = f2u(X[xbase + (size_t)c * 784 + p]);
    }
    __syncthreads();
    const size_t obase = ((size_t)b * 784 + pc * 112) * 256;
    for (int r = 0; r < 112; ++r) {
        int idx = r * 256 + t;
        int p = idx >> 8, c = idx & 255;
        O[obase + (size_t)p * 256 + c] = tile[c][p];
    }
}

// ---------------------------------------------------------------------------
// Depthwise 3x3 + affine + residual, NHWC bf16. Block=(h,b), thread=channel.
// ---------------------------------------------------------------------------
__global__ __launch_bounds__(256) void dw3n_k(const ushort* __restrict__ X,
                                              const float* __restrict__ Wg,
                                              const float* __restrict__ sc,
                                              const float* __restrict__ bi,
                                              ushort* __restrict__ O) {
    const int h = blockIdx.x, b = blockIdx.y;
    const int c = threadIdx.x;
    float wv[9];
#pragma unroll
    for (int k = 0; k < 9; ++k) wv[k] = Wg[c * 9 + k];
    const float s = sc[c], bb = bi[c];
    const size_t base = (size_t)b * 784 * 256;
    for (int w = 0; w < 28; ++w) {
        float acc = 0.f, ctr = 0.f;
#pragma unroll
        for (int dh = -1; dh <= 1; ++dh) {
            int hh = h + dh;
            if (hh < 0 || hh >= 28) continue;
#pragma unroll
            for (int dw = -1; dw <= 1; ++dw) {
                int ww = w + dw;
                if (ww < 0 || ww >= 28) continue;
                float xv = u2f(X[base + (size_t)(hh * 28 + ww) * 256 + c]);
                if (dh == 0 && dw == 0) ctr = xv;
                acc += wv[(dh + 1) * 3 + (dw + 1)] * xv;
            }
        }
        O[base + (size_t)(h * 28 + w) * 256 + c] = f2u(ctr + s * acc + bb);
    }
}

// ---------------------------------------------------------------------------
// MFMA GEMM, NHWC: Out[pos][oc] = s[oc]*(sum_ic X[pos][ic]*W[oc][ic]) + b[oc]
// 128x128 tile, BK=32, 4 waves, 16 mfma_f32_16x16x32_bf16 per wave per K-iter.
// Rows padded to 40 ushorts (80 B): frag b128 reads <=2-way bank aliased.
// ---------------------------------------------------------------------------
template <int IC, int OC, bool RELU_IN, bool RELU_OUT, bool RESID, bool NCHW_OUT>
__global__ __launch_bounds__(256) void gemm_k(const ushort* __restrict__ X,
                                              const ushort* __restrict__ Wb,
                                              const float* __restrict__ sc,
                                              const float* __restrict__ bi,
                                              const ushort* __restrict__ res,
                                              void* __restrict__ outp) {
    __shared__ ushort As[128 * 40];
    __shared__ ushort Bs[128 * 40];
    const int t = threadIdx.x;
    const int pos0 = blockIdx.x * 128;
    const int oc0  = blockIdx.y * 128;
    const int wave = t >> 6, lane = t & 63;
    const int qd = lane >> 4, ln = lane & 15;
    const int pw = (wave >> 1) * 64, ow = (wave & 1) * 64;
    const int srow = t >> 2, sc8 = t & 3;

    f32x4 acc[4][4];
#pragma unroll
    for (int i = 0; i < 4; ++i)
#pragma unroll
        for (int j = 0; j < 4; ++j) acc[i][j] = (f32x4)0.f;

    for (int k0 = 0; k0 < IC; k0 += 32) {
        __syncthreads();
#pragma unroll
        for (int r = 0; r < 2; ++r) {
            int row = srow + r * 64;
            uint4 xv = *(const uint4*)&X[(size_t)(pos0 + row) * IC + k0 + sc8 * 8];
            if constexpr (RELU_IN) {
                ushort* u = (ushort*)&xv;
#pragma unroll
                for (int e = 0; e < 8; ++e) u[e] = (u[e] & 0x8000) ? 0 : u[e];
            }
            *(uint4*)&As[row * 40 + sc8 * 8] = xv;
            uint4 wv = *(const uint4*)&Wb[(size_t)(oc0 + row) * IC + k0 + sc8 * 8];
            *(uint4*)&Bs[row * 40 + sc8 * 8] = wv;
        }
        __syncthreads();
        short8 bfr[4];
#pragma unroll
        for (int j = 0; j < 4; ++j)
            bfr[j] = *(const short8*)&Bs[(ow + j * 16 + ln) * 40 + qd * 8];
#pragma unroll
        for (int i = 0; i < 4; ++i) {
            short8 a = *(const short8*)&As[(pw + i * 16 + ln) * 40 + qd * 8];
#pragma unroll
            for (int j = 0; j < 4; ++j)
                acc[i][j] = __builtin_amdgcn_mfma_f32_16x16x32_bf16(a, bfr[j], acc[i][j], 0, 0, 0);
        }
    }

#pragma unroll
    for (int j = 0; j < 4; ++j) {
        const int oc = oc0 + ow + j * 16 + ln;
        const float s = sc[oc], bb = bi[oc];
#pragma unroll
        for (int i = 0; i < 4; ++i) {
#pragma unroll
            for (int r = 0; r < 4; ++r) {
                const int pos = pos0 + pw + i * 16 + qd * 4 + r;
                float v = s * acc[i][j][r] + bb;
                if constexpr (RELU_OUT) v = fmaxf(v, 0.f);
                if constexpr (RESID) v += u2f(res[(size_t)pos * 256 + oc]);
                if constexpr (NCHW_OUT) {
                    int bb2 = pos / 784, hw = pos - bb2 * 784;
                    ((float*)outp)[((size_t)bb2 * 256 + oc) * 784 + hw] = v;
                } else {
                    ((ushort*)outp)[(size_t)pos * OC + oc] = f2u(v);
                }
            }
        }
    }
}

// ---------------------------------------------------------------------------
// Cascaded group attention, NHWC bf16 in/out. One block per 7x7 window.
// Register-microtiled inner matmuls (4x4 / 2x4 outputs per thread).
// ---------------------------------------------------------------------------
__global__ __launch_bounds__(256) void attn_k(const ushort* __restrict__ X,
                                              const float* __restrict__ qkvW,
                                              const float* __restrict__ qkvS,
                                              const float* __restrict__ qkvB,
                                              const float* __restrict__ dwW,
                                              const float* __restrict__ dwS,
                                              const float* __restrict__ dwB,
                                              const float* __restrict__ ab,
                                              const int* __restrict__ bidx,
                                              ushort* __restrict__ Y) {
    __shared__ float feat[32][49];
    __shared__ float f[64][49];      // q 0:16, k 16:32, v 32:64
    __shared__ float q2[16][49];
    __shared__ float attn[49][51];   // stride 51: coprime with 32 banks
    __shared__ float qw[2048];
    __shared__ float qs[64], qb[64];
    __shared__ float dwv[400];
    __shared__ float dss[16], dbb[16];
    __shared__ float abr[49];
    __shared__ int idx_s[2401];
    __shared__ int posmap[49];

    const int t = threadIdx.x;
    const int w = blockIdx.x;
    const int b = w >> 4, wh = (w >> 2) & 3, ww = w & 3;

    if (t < 49) {
        int pi = t / 7, pj = t - pi * 7;
        posmap[t] = b * 784 + (wh * 7 + pi) * 28 + ww * 7 + pj;
    }
    for (int i = t; i < 2401; i += 256) idx_s[i] = bidx[i];
    __syncthreads();
    for (int i = t; i < 1568; i += 256) {
        int p = i >> 5, c = i & 31;
        feat[c][p] = u2f(X[(size_t)posmap[p] * 256 + c]);
    }

    for (int head = 0; head < 8; ++head) {
        if (head > 0) {
            for (int i = t; i < 1568; i += 256) {
                int p = i >> 5, c = i & 31;
                feat[c][p] += u2f(X[(size_t)posmap[p] * 256 + head * 32 + c]);
            }
        }
        for (int i = t; i < 2048; i += 256) qw[i] = qkvW[head * 2048 + i];
        if (t < 64) { qs[t] = qkvS[head * 64 + t]; qb[t] = qkvB[head * 64 + t]; }
        for (int i = t; i < 400; i += 256) dwv[i] = dwW[head * 400 + i];
        if (t < 16) { dss[t] = dwS[head * 16 + t]; dbb[t] = dwB[head * 16 + t]; }
        if (t < 49) abr[t] = ab[head * 49 + t];
        __syncthreads();

        // qkv 1x1: f[o][p], 4o x 4p per thread
        {
            const int ty = t >> 4, tx = t & 15;
            const int o0 = ty * 4;
            float accq[4][4] = {};
            for (int ic = 0; ic < 32; ++ic) {
                float wr[4], xr[4];
#pragma unroll
                for (int j = 0; j < 4; ++j) wr[j] = qw[(o0 + j) * 32 + ic];
#pragma unroll
                for (int i = 0; i < 4; ++i) {
                    int p = tx + 16 * i;
                    xr[i] = feat[ic][p < 49 ? p : 0];
                }
#pragma unroll
                for (int j = 0; j < 4; ++j)
#pragma unroll
                    for (int i = 0; i < 4; ++i) accq[j][i] += wr[j] * xr[i];
            }
#pragma unroll
            for (int j = 0; j < 4; ++j)
#pragma unroll
                for (int i = 0; i < 4; ++i) {
                    int p = tx + 16 * i;
                    if (p < 49) f[o0 + j][p] = qs[o0 + j] * accq[j][i] + qb[o0 + j];
                }
        }
        __syncthreads();

        // depthwise 5x5 on q
        for (int i = t; i < 784; i += 256) {
            int d = i / 49, p = i - d * 49;
            int pi = p / 7, pj = p - pi * 7;
            float a = 0.f;
            for (int u = 0; u < 5; ++u) {
                int ii = pi + u - 2;
                if (ii < 0 || ii >= 7) continue;
                for (int v = 0; v < 5; ++v) {
                    int jj = pj + v - 2;
                    if (jj < 0 || jj >= 7) continue;
                    a += dwv[d * 25 + u * 5 + v] * f[d][ii * 7 + jj];
                }
            }
            q2[d][p] = dss[d] * a + dbb[d];
        }
        __syncthreads();

        // logits: attn[n][m], 4n x 4m per thread (169 threads)
        if (t < 169) {
            int nb = t / 13, mb = t - nb * 13;
            float accl[4][4] = {};
            for (int d = 0; d < 16; ++d) {
                float qr[4], kr[4];
#pragma unroll
                for (int i = 0; i < 4; ++i) { int n = nb * 4 + i; qr[i] = q2[d][n < 49 ? n : 0]; }
#pragma unroll
                for (int j = 0; j < 4; ++j) { int m = mb * 4 + j; kr[j] = f[16 + d][m < 49 ? m : 0]; }
#pragma unroll
                for (int i = 0; i < 4; ++i)
#pragma unroll
                    for (int j = 0; j < 4; ++j) accl[i][j] += qr[i] * kr[j];
            }
#pragma unroll
            for (int i = 0; i < 4; ++i)
#pragma unroll
                for (int j = 0; j < 4; ++j) {
                    int n = nb * 4 + i, m = mb * 4 + j;
                    if (n < 49 && m < 49)
                        attn[n][m] = accl[i][j] * 0.25f + abr[idx_s[n * 49 + m]];
                }
        }
        __syncthreads();

        // softmax over m
        if (t < 49) {
            float mx = -1e30f;
            for (int m = 0; m < 49; ++m) mx = fmaxf(mx, attn[t][m]);
            float sum = 0.f;
            for (int m = 0; m < 49; ++m) {
                float e = __expf(attn[t][m] - mx);
                attn[t][m] = e;
                sum += e;
            }
            float inv = 1.f / sum;
            for (int m = 0; m < 49; ++m) attn[t][m] *= inv;
        }
        __syncthreads();

        // AV: feat[d][n] = sum_m v[d][m]*attn[n][m], 2d x 4n per thread (208 thr)
        if (t < 208) {
            int db = t / 13, nb = t - db * 13;
            float acca[2][4] = {};
            for (int m = 0; m < 49; ++m) {
                float vr[2], ar[4];
                vr[0] = f[32 + db * 2][m];
                vr[1] = f[33 + db * 2][m];
#pragma unroll
                for (int j = 0; j < 4; ++j) { int n = nb * 4 + j; ar[j] = attn[n < 49 ? n : 0][m]; }
#pragma unroll
                for (int i = 0; i < 2; ++i)
#pragma unroll
                    for (int j = 0; j < 4; ++j) acca[i][j] += vr[i] * ar[j];
            }
#pragma unroll
            for (int i = 0; i < 2; ++i)
#pragma unroll
                for (int j = 0; j < 4; ++j) {
                    int n = nb * 4 + j;
                    if (n < 49) feat[db * 2 + i][n] = acca[i][j];
                }
        }
        __syncthreads();

        // coalesced Y write (32 ch rows)
        for (int i = t; i < 1568; i += 256) {
            int p = i >> 5, c = i & 31;
            Y[(size_t)posmap[p] * 256 + head * 32 + c] = f2u(feat[c][p]);
        }
        __syncthreads();
    }
}

// ---------------------------------------------------------------------------
extern "C" void kernel_launch(void* const* d_in, const int* in_sizes, int n_in,
                              void* d_out, int out_size, void* d_ws, size_t ws_size,
                              hipStream_t stream) {
    const float* x       = (const float*)d_in[0];
    const float* dw0_w   = (const float*)d_in[1];
    const float* dw0_s   = (const float*)d_in[2];
    const float* dw0_b   = (const float*)d_in[3];
    const float* ffn0_w1 = (const float*)d_in[4];
    const float* ffn0_s1 = (const float*)d_in[5];
    const float* ffn0_b1 = (const float*)d_in[6];
    const float* ffn0_w2 = (const float*)d_in[7];
    const float* ffn0_s2 = (const float*)d_in[8];
    const float* ffn0_b2 = (const float*)d_in[9];
    const float* qkv_w   = (const float*)d_in[10];
    const float* qkv_s   = (const float*)d_in[11];
    const float* qkv_b   = (const float*)d_in[12];
    const float* dwq_w   = (const float*)d_in[13];
    const float* dwq_s   = (const float*)d_in[14];
    const float* dwq_b   = (const float*)d_in[15];
    const float* attn_b  = (const float*)d_in[16];
    const float* proj_w  = (const float*)d_in[17];
    const float* proj_s  = (const float*)d_in[18];
    const float* proj_b  = (const float*)d_in[19];
    const float* dw1_w   = (const float*)d_in[20];
    const float* dw1_s   = (const float*)d_in[21];
    const float* dw1_b   = (const float*)d_in[22];
    const float* ffn1_w1 = (const float*)d_in[23];
    const float* ffn1_s1 = (const float*)d_in[24];
    const float* ffn1_b1 = (const float*)d_in[25];
    const float* ffn1_w2 = (const float*)d_in[26];
    const float* ffn1_s2 = (const float*)d_in[27];
    const float* ffn1_b2 = (const float*)d_in[28];
    const int*   bidx    = (const int*)d_in[29];

    char* ws = (char*)d_ws;
    const size_t NEL = (size_t)NPOS * 256;           // 25,690,112 elements
    ushort* wbf = (ushort*)ws;                        // 589,824 bf16 weights
    ushort* U0 = (ushort*)(ws + 1179648);             // Xn -> Y
    ushort* U1 = U0 + NEL;                            // R1 -> R3
    ushort* U2 = U1 + NEL;                            // R2 -> R4
    ushort* H  = U2 + NEL;                            // hidden [pos][512]
    const ushort* w1a_b = wbf;
    const ushort* w2a_b = wbf + 131072;
    const ushort* prj_b = wbf + 262144;
    const ushort* w1b_b = wbf + 327680;
    const ushort* w2b_b = wbf + 458752;

    wcvt_k<<<2304, 256, 0, stream>>>(ffn0_w1, ffn0_w2, proj_w, ffn1_w1, ffn1_w2, wbf);
    tin_k<<<dim3(7, BATCH), 256, 0, stream>>>(x, U0);
    dw3n_k<<<dim3(28, BATCH), 256, 0, stream>>>(U0, dw0_w, dw0_s, dw0_b, U1);
    gemm_k<256, 512, false, true, false, false>
        <<<dim3(784, 4), 256, 0, stream>>>(U1, w1a_b, ffn0_s1, ffn0_b1, nullptr, H);
    gemm_k<512, 256, false, false, true, false>
        <<<dim3(784, 2), 256, 0, stream>>>(H, w2a_b, ffn0_s2, ffn0_b2, U1, U2);
    attn_k<<<NWIN, 256, 0, stream>>>(U2, qkv_w, qkv_s, qkv_b, dwq_w, dwq_s, dwq_b,
                                     attn_b, bidx, U0);
    gemm_k<256, 256, true, false, true, false>
        <<<dim3(784, 2), 256, 0, stream>>>(U0, prj_b, proj_s, proj_b, U2, U1);
    dw3n_k<<<dim3(28, BATCH), 256, 0, stream>>>(U1, dw1_w, dw1_s, dw1_b, U2);
    gemm_k<256, 512, false, true, false, false>
        <<<dim3(784, 4), 256, 0, stream>>>(U2, w1b_b, ffn1_s1, ffn1_b1, nullptr, H);
    gemm_k<512, 256, false, false, true, true>
        <<<dim3(784, 2), 256, 0, stream>>>(H, w2b_b, ffn1_s2, ffn1_b2, U2, d_out);
}

// Round 4
// 1307.267 us; speedup vs baseline: 2.0584x; 1.4679x over previous
//
#include <hip/hip_runtime.h>
#include <hip/hip_bf16.h>

using bf16 = __hip_bfloat16;
using short8 = __attribute__((ext_vector_type(8))) short;
using f32x4  = __attribute__((ext_vector_type(4))) float;

#define BATCH 128
#define CCH   256
#define HWSZ  784
#define NPOS  100352
#define NWIN  2048

__device__ __forceinline__ ushort f2u(float f) {
    bf16 h = __float2bfloat16(f);
    return *reinterpret_cast<ushort*>(&h);
}
__device__ __forceinline__ float u2f(ushort u) {
    bf16 h;
    *reinterpret_cast<ushort*>(&h) = u;
    return __bfloat162float(h);
}

// ---------------------------------------------------------------------------
// Weight fp32 -> bf16 pre-convert (5 matrices concatenated).
// ---------------------------------------------------------------------------
__global__ __launch_bounds__(256) void wcvt_k(const float* __restrict__ w1a,
                                              const float* __restrict__ w2a,
                                              const float* __restrict__ pw,
                                              const float* __restrict__ w1b,
                                              const float* __restrict__ w2b,
                                              ushort* __restrict__ out) {
    int i = blockIdx.x * 256 + threadIdx.x;
    if (i >= 589824) return;
    float v;
    if (i < 131072)      v = w1a[i];
    else if (i < 262144) v = w2a[i - 131072];
    else if (i < 327680) v = pw[i - 262144];
    else if (i < 458752) v = w1b[i - 327680];
    else                 v = w2b[i - 458752];
    out[i] = f2u(v);
}

// ---------------------------------------------------------------------------
// Expand attention biases: abx[h][n][m] = ab[h][bidx[n*49+m]]  (8 x 49 x 49)
// ---------------------------------------------------------------------------
__global__ __launch_bounds__(256) void abx_k(const float* __restrict__ ab,
                                             const int* __restrict__ bidx,
                                             float* __restrict__ abx) {
    int i = blockIdx.x * 256 + threadIdx.x;
    if (i >= 8 * 2401) return;
    int h = i / 2401, r = i - h * 2401;
    abx[i] = ab[h * 49 + bidx[r]];
}

// ---------------------------------------------------------------------------
// NCHW fp32 -> NHWC bf16 transpose.
// ---------------------------------------------------------------------------
__global__ __launch_bounds__(256) void tin_k(const float* __restrict__ X,
                                             ushort* __restrict__ O) {
    __shared__ ushort tile[256][113];
    const int pc = blockIdx.x, b = blockIdx.y;
    const int t = threadIdx.x;
    const size_t xbase = (size_t)b * 256 * 784 + pc * 112;
    for (int r = 0; r < 112; ++r) {
        int idx = r * 256 + t;
        int c = idx / 112, p = idx - c * 112;
        tile[c][p] = f2u(X[xbase + (size_t)c * 784 + p]);
    }
    __syncthreads();
    const size_t obase = ((size_t)b * 784 + pc * 112) * 256;
    for (int r = 0; r < 112; ++r) {
        int idx = r * 256 + t;
        int p = idx >> 8, c = idx & 255;
        O[obase + (size_t)p * 256 + c] = tile[c][p];
    }
}

// ---------------------------------------------------------------------------
// Depthwise 3x3 + affine + residual, NHWC bf16.
// ---------------------------------------------------------------------------
__global__ __launch_bounds__(256) void dw3n_k(const ushort* __restrict__ X,
                                              const float* __restrict__ Wg,
                                              const float* __restrict__ sc,
                                              const float* __restrict__ bi,
                                              ushort* __restrict__ O) {
    const int h = blockIdx.x, b = blockIdx.y;
    const int c = threadIdx.x;
    float wv[9];
#pragma unroll
    for (int k = 0; k < 9; ++k) wv[k] = Wg[c * 9 + k];
    const float s = sc[c], bb = bi[c];
    const size_t base = (size_t)b * 784 * 256;
    for (int w = 0; w < 28; ++w) {
        float acc = 0.f, ctr = 0.f;
#pragma unroll
        for (int dh = -1; dh <= 1; ++dh) {
            int hh = h + dh;
            if (hh < 0 || hh >= 28) continue;
#pragma unroll
            for (int dw = -1; dw <= 1; ++dw) {
                int ww = w + dw;
                if (ww < 0 || ww >= 28) continue;
                float xv = u2f(X[base + (size_t)(hh * 28 + ww) * 256 + c]);
                if (dh == 0 && dw == 0) ctr = xv;
                acc += wv[(dh + 1) * 3 + (dw + 1)] * xv;
            }
        }
        O[base + (size_t)(h * 28 + w) * 256 + c] = f2u(ctr + s * acc + bb);
    }
}

// ---------------------------------------------------------------------------
// MFMA GEMM, NHWC (unchanged from round 3 — passing & fast).
// ---------------------------------------------------------------------------
template <int IC, int OC, bool RELU_IN, bool RELU_OUT, bool RESID, bool NCHW_OUT>
__global__ __launch_bounds__(256) void gemm_k(const ushort* __restrict__ X,
                                              const ushort* __restrict__ Wb,
                                              const float* __restrict__ sc,
                                              const float* __restrict__ bi,
                                              const ushort* __restrict__ res,
                                              void* __restrict__ outp) {
    __shared__ ushort As[128 * 40];
    __shared__ ushort Bs[128 * 40];
    const int t = threadIdx.x;
    const int pos0 = blockIdx.x * 128;
    const int oc0  = blockIdx.y * 128;
    const int wave = t >> 6, lane = t & 63;
    const int qd = lane >> 4, ln = lane & 15;
    const int pw = (wave >> 1) * 64, ow = (wave & 1) * 64;
    const int srow = t >> 2, sc8 = t & 3;

    f32x4 acc[4][4];
#pragma unroll
    for (int i = 0; i < 4; ++i)
#pragma unroll
        for (int j = 0; j < 4; ++j) acc[i][j] = (f32x4)0.f;

    for (int k0 = 0; k0 < IC; k0 += 32) {
        __syncthreads();
#pragma unroll
        for (int r = 0; r < 2; ++r) {
            int row = srow + r * 64;
            uint4 xv = *(const uint4*)&X[(size_t)(pos0 + row) * IC + k0 + sc8 * 8];
            if constexpr (RELU_IN) {
                ushort* u = (ushort*)&xv;
#pragma unroll
                for (int e = 0; e < 8; ++e) u[e] = (u[e] & 0x8000) ? 0 : u[e];
            }
            *(uint4*)&As[row * 40 + sc8 * 8] = xv;
            uint4 wv = *(const uint4*)&Wb[(size_t)(oc0 + row) * IC + k0 + sc8 * 8];
            *(uint4*)&Bs[row * 40 + sc8 * 8] = wv;
        }
        __syncthreads();
        short8 bfr[4];
#pragma unroll
        for (int j = 0; j < 4; ++j)
            bfr[j] = *(const short8*)&Bs[(ow + j * 16 + ln) * 40 + qd * 8];
#pragma unroll
        for (int i = 0; i < 4; ++i) {
            short8 a = *(const short8*)&As[(pw + i * 16 + ln) * 40 + qd * 8];
#pragma unroll
            for (int j = 0; j < 4; ++j)
                acc[i][j] = __builtin_amdgcn_mfma_f32_16x16x32_bf16(a, bfr[j], acc[i][j], 0, 0, 0);
        }
    }

#pragma unroll
    for (int j = 0; j < 4; ++j) {
        const int oc = oc0 + ow + j * 16 + ln;
        const float s = sc[oc], bb = bi[oc];
#pragma unroll
        for (int i = 0; i < 4; ++i) {
#pragma unroll
            for (int r = 0; r < 4; ++r) {
                const int pos = pos0 + pw + i * 16 + qd * 4 + r;
                float v = s * acc[i][j][r] + bb;
                if constexpr (RELU_OUT) v = fmaxf(v, 0.f);
                if constexpr (RESID) v += u2f(res[(size_t)pos * 256 + oc]);
                if constexpr (NCHW_OUT) {
                    int bb2 = pos / 784, hw = pos - bb2 * 784;
                    ((float*)outp)[((size_t)bb2 * 256 + oc) * 784 + hw] = v;
                } else {
                    ((ushort*)outp)[(size_t)pos * OC + oc] = f2u(v);
                }
            }
        }
    }
}

// ---------------------------------------------------------------------------
// Cascaded group attention, MFMA version. One block per 7x7 window.
// All matmuls as 16x16x32 bf16 MFMA over zero-padded 64x64 tiles.
// Wave w owns tile-row w of each matmul.
// ---------------------------------------------------------------------------
__global__ __launch_bounds__(256, 3) void attn_k(const ushort* __restrict__ X,
                                                 const float* __restrict__ qkvW,
                                                 const float* __restrict__ qkvS,
                                                 const float* __restrict__ qkvB,
                                                 const float* __restrict__ dwW,
                                                 const float* __restrict__ dwS,
                                                 const float* __restrict__ dwB,
                                                 const float* __restrict__ abx,
                                                 ushort* __restrict__ Y) {
    __shared__ float  featF[64 * 32];   // pos-major fp32 feat
    __shared__ ushort featB[64 * 32];   // bf16 copy (MFMA B operand)
    __shared__ ushort qw[64 * 32];      // qkv weight bf16 (A operand)
    __shared__ ushort q2t[64 * 32];     // q after dw5x5, pos-major, K-pad 32
    __shared__ ushort kt[64 * 32];      // k, pos-major, K-pad 32
    __shared__ ushort vd[32 * 64];      // v, ch-major, m-pad 64
    __shared__ ushort pt[64 * 64];      // softmax probs, pos-major, m-pad 64
    __shared__ float  uni[64 * 52];     // union: qch[16][52] then attnF[64][52]
    __shared__ float  qs[64], qb[64];
    __shared__ float  dwv[400];
    __shared__ float  dss[16], dbb[16];
    __shared__ float  red[49 * 6];
    __shared__ float  rm[49];
    __shared__ int    posmap[49];

    const int t = threadIdx.x;
    const int w = blockIdx.x;
    const int b = w >> 4, wh = (w >> 2) & 3, ww = w & 3;
    const int wv_ = t >> 6, lane = t & 63;
    const int ln = lane & 15, qd = lane >> 4;

    if (t < 49) {
        int pi = t / 7, pj = t - pi * 7;
        posmap[t] = b * 784 + (wh * 7 + pi) * 28 + ww * 7 + pj;
    }
    // zero-init padded operand buffers (pads never rewritten)
    for (int i = t; i < 64 * 32; i += 256) { q2t[i] = 0; kt[i] = 0; }
    for (int i = t; i < 32 * 64; i += 256) vd[i] = 0;
    for (int i = t; i < 64 * 64; i += 256) pt[i] = 0;
    __syncthreads();
    // feat = x2 slice 0 (positions >=49 zero)
    for (int i = t; i < 64 * 32; i += 256) {
        int p = i >> 5, c = i & 31;
        featF[i] = (p < 49) ? u2f(X[(size_t)posmap[p] * 256 + c]) : 0.f;
    }

    for (int head = 0; head < 8; ++head) {
        // ---- stage per-head weights + bf16 feat ----
        for (int i = t; i < 2048; i += 256) {
            featB[i] = f2u(featF[i]);
            qw[i] = f2u(qkvW[head * 2048 + i]);
        }
        if (t < 64) { qs[t] = qkvS[head * 64 + t]; qb[t] = qkvB[head * 64 + t]; }
        for (int i = t; i < 400; i += 256) dwv[i] = dwW[head * 400 + i];
        if (t < 16) { dss[t] = dwS[head * 16 + t]; dbb[t] = dwB[head * 16 + t]; }
        __syncthreads();

        // ---- qkv: D[o][p] = qw[o][:]·featB[p][:]  (wave = o-tile) ----
        {
            short8 afr = *(const short8*)&qw[(16 * wv_ + ln) * 32 + qd * 8];
            f32x4 acc[4];
#pragma unroll
            for (int j = 0; j < 4; ++j) acc[j] = (f32x4)0.f;
#pragma unroll
            for (int j = 0; j < 4; ++j) {
                short8 bfr = *(const short8*)&featB[(16 * j + ln) * 32 + qd * 8];
                acc[j] = __builtin_amdgcn_mfma_f32_16x16x32_bf16(afr, bfr, acc[j], 0, 0, 0);
            }
#pragma unroll
            for (int j = 0; j < 4; ++j) {
                int p = 16 * j + ln;
                if (p >= 49) continue;
#pragma unroll
                for (int r = 0; r < 4; ++r) {
                    int o = 16 * wv_ + qd * 4 + r;
                    float v = qs[o] * acc[j][r] + qb[o];
                    if (wv_ == 0)      uni[o * 52 + p] = v;              // q ch-major
                    else if (wv_ == 1) kt[p * 32 + (o - 16)] = f2u(v);   // k pos-major
                    else               vd[(o - 32) * 64 + p] = f2u(v);   // v ch-major
                }
            }
        }
        __syncthreads();

        // ---- depthwise 5x5 on q -> q2t (pos-major, bf16) ----
        for (int i = t; i < 784; i += 256) {
            int d = i / 49, p = i - d * 49;
            int pi = p / 7, pj = p - pi * 7;
            float a = 0.f;
            for (int u = 0; u < 5; ++u) {
                int ii = pi + u - 2;
                if (ii < 0 || ii >= 7) continue;
                for (int v = 0; v < 5; ++v) {
                    int jj = pj + v - 2;
                    if (jj < 0 || jj >= 7) continue;
                    a += dwv[d * 25 + u * 5 + v] * uni[d * 52 + ii * 7 + jj];
                }
            }
            q2t[p * 32 + d] = f2u(dss[d] * a + dbb[d]);
        }
        __syncthreads();

        // ---- logits: D[n][m] = q2t[n][:]·kt[m][:]  (wave = n-tile) ----
        {
            short8 afr = *(const short8*)&q2t[(16 * wv_ + ln) * 32 + qd * 8];
            f32x4 acc[4];
#pragma unroll
            for (int j = 0; j < 4; ++j) acc[j] = (f32x4)0.f;
#pragma unroll
            for (int j = 0; j < 4; ++j) {
                short8 bfr = *(const short8*)&kt[(16 * j + ln) * 32 + qd * 8];
                acc[j] = __builtin_amdgcn_mfma_f32_16x16x32_bf16(afr, bfr, acc[j], 0, 0, 0);
            }
#pragma unroll
            for (int j = 0; j < 4; ++j) {
                int m = 16 * j + ln;
                if (m >= 49) continue;
#pragma unroll
                for (int r = 0; r < 4; ++r) {
                    int n = 16 * wv_ + qd * 4 + r;
                    if (n < 49)
                        uni[n * 52 + m] = acc[j][r] * 0.25f +
                                          abx[head * 2401 + n * 49 + m];
                }
            }
        }
        __syncthreads();

        // ---- softmax over m (rows n), probs -> pt bf16, 1/sum -> rm ----
        if (t < 245) {
            int n = t / 5, s = t % 5;
            int m0 = s * 10, m1 = m0 + 10 > 49 ? 49 : m0 + 10;
            float mx = -1e30f;
            for (int m = m0; m < m1; ++m) mx = fmaxf(mx, uni[n * 52 + m]);
            red[n * 6 + s] = mx;
        }
        __syncthreads();
        if (t < 49) {
            float mx = red[t * 6];
            for (int s = 1; s < 5; ++s) mx = fmaxf(mx, red[t * 6 + s]);
            rm[t] = mx;
        }
        __syncthreads();
        if (t < 245) {
            int n = t / 5, s = t % 5;
            int m0 = s * 10, m1 = m0 + 10 > 49 ? 49 : m0 + 10;
            float sum = 0.f, mx = rm[n];
            for (int m = m0; m < m1; ++m) {
                float e = __expf(uni[n * 52 + m] - mx);
                pt[n * 64 + m] = f2u(e);
                sum += e;
            }
            red[n * 6 + s] = sum;
        }
        __syncthreads();
        if (t < 49) {
            float sum = 0.f;
            for (int s = 0; s < 5; ++s) sum += red[t * 6 + s];
            rm[t] = 1.f / sum;
        }
        __syncthreads();

        // ---- AV: D[n][d] = pt[n][:]·vd[d][:], scaled by rm[n] -> featF ----
        {
            short8 a0 = *(const short8*)&pt[(16 * wv_ + ln) * 64 + qd * 8];
            short8 a1 = *(const short8*)&pt[(16 * wv_ + ln) * 64 + 32 + qd * 8];
            f32x4 acc[2];
            acc[0] = (f32x4)0.f; acc[1] = (f32x4)0.f;
#pragma unroll
            for (int dt = 0; dt < 2; ++dt) {
                short8 b0 = *(const short8*)&vd[(16 * dt + ln) * 64 + qd * 8];
                short8 b1 = *(const short8*)&vd[(16 * dt + ln) * 64 + 32 + qd * 8];
                acc[dt] = __builtin_amdgcn_mfma_f32_16x16x32_bf16(a0, b0, acc[dt], 0, 0, 0);
                acc[dt] = __builtin_amdgcn_mfma_f32_16x16x32_bf16(a1, b1, acc[dt], 0, 0, 0);
            }
#pragma unroll
            for (int dt = 0; dt < 2; ++dt) {
#pragma unroll
                for (int r = 0; r < 4; ++r) {
                    int n = 16 * wv_ + qd * 4 + r;
                    if (n < 49)
                        featF[n * 32 + 16 * dt + ln] = acc[dt][r] * rm[n];
                }
            }
        }
        __syncthreads();

        // ---- emit Y slice; feat += next x2 slice ----
        for (int i = t; i < 1568; i += 256) {
            int p = i >> 5, c = i & 31;
            float v = featF[p * 32 + c];
            Y[(size_t)posmap[p] * 256 + head * 32 + c] = f2u(v);
            if (head < 7)
                featF[p * 32 + c] = v + u2f(X[(size_t)posmap[p] * 256 + (head + 1) * 32 + c]);
        }
        __syncthreads();
    }
}

// ---------------------------------------------------------------------------
extern "C" void kernel_launch(void* const* d_in, const int* in_sizes, int n_in,
                              void* d_out, int out_size, void* d_ws, size_t ws_size,
                              hipStream_t stream) {
    const float* x       = (const float*)d_in[0];
    const float* dw0_w   = (const float*)d_in[1];
    const float* dw0_s   = (const float*)d_in[2];
    const float* dw0_b   = (const float*)d_in[3];
    const float* ffn0_w1 = (const float*)d_in[4];
    const float* ffn0_s1 = (const float*)d_in[5];
    const float* ffn0_b1 = (const float*)d_in[6];
    const float* ffn0_w2 = (const float*)d_in[7];
    const float* ffn0_s2 = (const float*)d_in[8];
    const float* ffn0_b2 = (const float*)d_in[9];
    const float* qkv_w   = (const float*)d_in[10];
    const float* qkv_s   = (const float*)d_in[11];
    const float* qkv_b   = (const float*)d_in[12];
    const float* dwq_w   = (const float*)d_in[13];
    const float* dwq_s   = (const float*)d_in[14];
    const float* dwq_b   = (const float*)d_in[15];
    const float* attn_b  = (const float*)d_in[16];
    const float* proj_w  = (const float*)d_in[17];
    const float* proj_s  = (const float*)d_in[18];
    const float* proj_b  = (const float*)d_in[19];
    const float* dw1_w   = (const float*)d_in[20];
    const float* dw1_s   = (const float*)d_in[21];
    const float* dw1_b   = (const float*)d_in[22];
    const float* ffn1_w1 = (const float*)d_in[23];
    const float* ffn1_s1 = (const float*)d_in[24];
    const float* ffn1_b1 = (const float*)d_in[25];
    const float* ffn1_w2 = (const float*)d_in[26];
    const float* ffn1_s2 = (const float*)d_in[27];
    const float* ffn1_b2 = (const float*)d_in[28];
    const int*   bidx    = (const int*)d_in[29];

    char* ws = (char*)d_ws;
    const size_t NEL = (size_t)NPOS * 256;
    ushort* wbf = (ushort*)ws;                          // 1,179,648 B
    float*  abx = (float*)(ws + 1179648);               // 76,832 B
    ushort* U0 = (ushort*)(ws + 1257472);
    ushort* U1 = U0 + NEL;
    ushort* U2 = U1 + NEL;
    ushort* H  = U2 + NEL;
    const ushort* w1a_b = wbf;
    const ushort* w2a_b = wbf + 131072;
    const ushort* prj_b = wbf + 262144;
    const ushort* w1b_b = wbf + 327680;
    const ushort* w2b_b = wbf + 458752;

    wcvt_k<<<2304, 256, 0, stream>>>(ffn0_w1, ffn0_w2, proj_w, ffn1_w1, ffn1_w2, wbf);
    abx_k<<<76, 256, 0, stream>>>(attn_b, bidx, abx);
    tin_k<<<dim3(7, BATCH), 256, 0, stream>>>(x, U0);
    dw3n_k<<<dim3(28, BATCH), 256, 0, stream>>>(U0, dw0_w, dw0_s, dw0_b, U1);
    gemm_k<256, 512, false, true, false, false>
        <<<dim3(784, 4), 256, 0, stream>>>(U1, w1a_b, ffn0_s1, ffn0_b1, nullptr, H);
    gemm_k<512, 256, false, false, true, false>
        <<<dim3(784, 2), 256, 0, stream>>>(H, w2a_b, ffn0_s2, ffn0_b2, U1, U2);
    attn_k<<<NWIN, 256, 0, stream>>>(U2, qkv_w, qkv_s, qkv_b, dwq_w, dwq_s, dwq_b,
                                     abx, U0);
    gemm_k<256, 256, true, false, true, false>
        <<<dim3(784, 2), 256, 0, stream>>>(U0, prj_b, proj_s, proj_b, U2, U1);
    dw3n_k<<<dim3(28, BATCH), 256, 0, stream>>>(U1, dw1_w, dw1_s, dw1_b, U2);
    gemm_k<256, 512, false, true, false, false>
        <<<dim3(784, 4), 256, 0, stream>>>(U2, w1b_b, ffn1_s1, ffn1_b1, nullptr, H);
    gemm_k<512, 256, false, false, true, true>
        <<<dim3(784, 2), 256, 0, stream>>>(H, w2b_b, ffn1_s2, ffn1_b2, U2, d_out);
}